// Round 1
// baseline (3049.663 us; speedup 1.0000x reference)
//
#include <hip/hip_runtime.h>
#include <math.h>

#define NB 4
#define NC 20
#define NH 480
#define NW 640
#define NM 480
#define NVR 100
#define NNZ 80
#define ZLO 13
#define ZHI 25
#define NZB 12
#define NSEM_ 16

// ---------------- pose + affine params ----------------
__global__ __launch_bounds__(64) void pose_kernel(
    const float* __restrict__ pose_obs, const float* __restrict__ poses_last,
    float* __restrict__ out_poses, float* __restrict__ params)
{
  int b = threadIdx.x;
  if (b >= NB) return;
  const float R2D = 57.29577951308232f;
  float plx = poses_last[b*3+0], ply = poses_last[b*3+1], plo = poses_last[b*3+2];
  float dx = pose_obs[b*3+0], dy = pose_obs[b*3+1], dth = pose_obs[b*3+2];
  float r = plo / R2D;
  float sr = sinf(r), cr = cosf(r);
  float yy = ply + dx*sr + dy*cr;
  float xx = plx + dx*cr - dy*sr;
  float oo = plo + dth*R2D;
  oo = fmodf(oo - 180.0f, 360.0f) + 180.0f;
  oo = fmodf(oo + 180.0f, 360.0f) - 180.0f;
  out_poses[b*3+0] = xx;
  out_poses[b*3+1] = yy;
  out_poses[b*3+2] = oo;
  // st_xy = -(pose*100/RES - M//2)/(M//2)
  float tx = -((xx*100.0f/5.0f) - 240.0f) / 240.0f;
  float ty = -((yy*100.0f/5.0f) - 240.0f) / 240.0f;
  float th = ((90.0f - oo) * 3.14159274101257324f) / 180.0f; // np.pi as f32
  params[b*4+0] = cosf(th);
  params[b*4+1] = sinf(th);
  params[b*4+2] = tx;
  params[b*4+3] = ty;
}

// ---------------- trilinear splat (atomics) ----------------
// vox0: [b][x:100][y:100][z:80]            (channel 0, full z)
// vox1: [b][x:100][y:100][zb:12][s:16]     (channels 1..16, z in [13,25))
__global__ __launch_bounds__(256) void splat_kernel(
    const float* __restrict__ obs, float* __restrict__ vox0,
    float* __restrict__ vox1, float foc)
{
  int tid = blockIdx.x * 256 + threadIdx.x;
  int b = tid / (NH*NW);
  int rem = tid - b*(NH*NW);
  int row = rem / NW;
  int col = rem - row*NW;

  float d = obs[(((size_t)b*NC + 3)*NH + row)*NW + col];
  // point cloud (replicating reference f32 op order)
  float X = ((float)col - 319.5f) * d / foc;
  float Z = ((float)(479 - row) - 239.5f) * d / foc;
  float xy0 = (X + 250.0f) / 5.0f;
  float xy1 = d / 5.0f;
  xy0 = (xy0 - 50.0f) / 100.0f * 2.0f;
  xy1 = (xy1 - 50.0f) / 100.0f * 2.0f;
  float zz = (Z + 88.0f) / 5.0f;
  zz = (zz - 32.0f) / 80.0f * 2.0f;
  float p0 = xy0 * 50.0f + 50.0f;   // == (X+250)/5 up to fp assoc
  float p1 = xy1 * 50.0f + 50.0f;
  float p2 = zz * 40.0f + 40.0f;

  float fl0 = floorf(p0), fl1 = floorf(p1), fl2 = floorf(p2);
  float wx[2], wy[2], wz[2];
  int ix[2], iy[2], iz[2];
  #pragma unroll
  for (int o = 0; o < 2; ++o) {
    float px = fl0 + (float)o;
    bool s = (px > 0.0f) && (px < 100.0f);
    wx[o] = s ? (1.0f - fabsf(p0 - px)) : 0.0f;
    ix[o] = s ? (int)px : 0;
    float py = fl1 + (float)o;
    s = (py > 0.0f) && (py < 100.0f);
    wy[o] = s ? (1.0f - fabsf(p1 - py)) : 0.0f;
    iy[o] = s ? (int)py : 0;
    float pz = fl2 + (float)o;
    s = (pz > 0.0f) && (pz < 80.0f);
    wz[o] = s ? (1.0f - fabsf(p2 - pz)) : 0.0f;
    iz[o] = s ? (int)pz : 0;
  }

  bool band = false;
  #pragma unroll
  for (int a = 0; a < 2; ++a) {
    if (wx[a] <= 0.0f) continue;
    #pragma unroll
    for (int c = 0; c < 2; ++c) {
      float wxy = wx[a]*wy[c];
      if (wxy <= 0.0f) continue;
      #pragma unroll
      for (int e = 0; e < 2; ++e) {
        float w = wxy * wz[e];
        if (w > 0.0f) {
          unsafeAtomicAdd(&vox0[(((size_t)b*NVR + ix[a])*NVR + iy[c])*NNZ + iz[e]], w);
          if (iz[e] >= ZLO && iz[e] < ZHI) band = true;
        }
      }
    }
  }
  if (!band) return;

  float sem[NSEM_];
  #pragma unroll
  for (int s = 0; s < NSEM_; ++s)
    sem[s] = obs[(((size_t)b*NC + 4 + s)*NH + row)*NW + col];

  #pragma unroll
  for (int a = 0; a < 2; ++a) {
    if (wx[a] <= 0.0f) continue;
    #pragma unroll
    for (int c = 0; c < 2; ++c) {
      float wxy = wx[a]*wy[c];
      if (wxy <= 0.0f) continue;
      #pragma unroll
      for (int e = 0; e < 2; ++e) {
        float w = wxy * wz[e];
        if (w > 0.0f && iz[e] >= ZLO && iz[e] < ZHI) {
          float* base = &vox1[((((size_t)b*NVR + ix[a])*NVR + iy[c])*NZB + (iz[e]-ZLO))*NSEM_];
          #pragma unroll
          for (int s = 0; s < NSEM_; ++s)
            unsafeAtomicAdd(&base[s], w * sem[s]);
        }
      }
    }
  }
}

// ---------------- round + z-projection -> 100x100 patch ----------------
// proj: [b][c:20][i:100][j:100]  (agent_view channel values inside the patch)
__global__ __launch_bounds__(256) void project_kernel(
    const float* __restrict__ vox0, const float* __restrict__ vox1,
    float* __restrict__ proj, float* __restrict__ out_fp)
{
  int tid = blockIdx.x * 256 + threadIdx.x;
  if (tid >= NB*NVR*NVR) return;
  int b = tid / (NVR*NVR);
  int rem = tid - b*(NVR*NVR);
  int i = rem / NVR;    // d1 (depth axis -> map row)
  int j = rem - i*NVR;  // d0 (lateral -> map col)

  const float* v0 = vox0 + (((size_t)b*NVR + j)*NVR + i)*NNZ;
  float s_all = 0.0f, s_ag = 0.0f;
  for (int z = 0; z < NNZ; ++z) {
    float v = rintf(v0[z]);      // RNE, matches jnp.round
    s_all += v;
    if (z >= ZLO && z < ZHI) s_ag += v;
  }
  float fp_map = fminf(fmaxf(s_ag, 0.0f), 1.0f);   // MAP_THR=1
  float fp_exp = fminf(fmaxf(s_all, 0.0f), 1.0f);  // EXP_THR=1

  size_t pb = (size_t)b*NC*NVR*NVR + (size_t)i*NVR + j;
  proj[pb + 0*NVR*NVR] = fp_map;
  proj[pb + 1*NVR*NVR] = fp_exp;
  proj[pb + 2*NVR*NVR] = 0.0f;
  proj[pb + 3*NVR*NVR] = 0.0f;
  const float* v1 = vox1 + (((size_t)b*NVR + j)*NVR + i)*NZB*NSEM_;
  #pragma unroll
  for (int s = 0; s < NSEM_; ++s) {
    float acc = 0.0f;
    for (int z = 0; z < NZB; ++z) acc += rintf(v1[z*NSEM_ + s]);
    proj[pb + (size_t)(4+s)*NVR*NVR] = fminf(fmaxf(acc / 5.0f, 0.0f), 1.0f); // CAT_THR=5
  }
  out_fp[(size_t)b*NVR*NVR + (size_t)i*NVR + j] = fp_map;
}

// ---------------- fused rotate+translate grid_sample + max ----------------
__global__ __launch_bounds__(256) void transform_kernel(
    const float* __restrict__ maps_last, const float* __restrict__ proj,
    const float* __restrict__ params, float* __restrict__ d_out)
{
  int tid = blockIdx.x * 256 + threadIdx.x;
  int b = tid / (NM*NM);
  int rem = tid - b*(NM*NM);
  int h = rem / NM;
  int w = rem - h*NM;

  float ct = params[b*4+0];
  float st = params[b*4+1];
  float tx = params[b*4+2];
  float ty = params[b*4+3];

  const float step = 2.0f/479.0f;
  float gx = -1.0f + (float)w * step;
  float gy = -1.0f + (float)h * step;
  // translation grid -> pixel coords in `rotated`
  float X2 = ((gx + tx) + 1.0f) * 0.5f * 479.0f;
  float Y2 = ((gy + ty) + 1.0f) * 0.5f * 479.0f;
  float x0 = floorf(X2), y0 = floorf(Y2);
  float wox[2] = {(x0 + 1.0f) - X2, X2 - x0};
  float woy[2] = {(y0 + 1.0f) - Y2, Y2 - y0};

  float twt[16];
  int   toff[16];
  int nz = 0;
  #pragma unroll
  for (int oy = 0; oy < 2; ++oy) {
    #pragma unroll
    for (int ox = 0; ox < 2; ++ox) {
      int kb = (oy*2 + ox)*4;
      float cx = x0 + (float)ox;
      float cy = y0 + (float)oy;
      float wo = wox[ox]*woy[oy];
      bool ov = (cx >= 0.0f) && (cx <= 479.0f) && (cy >= 0.0f) && (cy <= 479.0f);
      if (ov) {
        // rotated value at integer pixel (cy,cx) = bilinear sample of agent_view
        float gxr = -1.0f + cx * step;
        float gyr = -1.0f + cy * step;
        float xr = gxr*ct - gyr*st;
        float yr = gxr*st + gyr*ct;
        float XS = (xr + 1.0f)*0.5f*479.0f;
        float YS = (yr + 1.0f)*0.5f*479.0f;
        float ix0 = floorf(XS), iy0 = floorf(YS);
        float wix[2] = {(ix0+1.0f)-XS, XS-ix0};
        float wiy[2] = {(iy0+1.0f)-YS, YS-iy0};
        #pragma unroll
        for (int qy = 0; qy < 2; ++qy) {
          #pragma unroll
          for (int qx = 0; qx < 2; ++qx) {
            int k = kb + qy*2 + qx;
            float ux = ix0 + (float)qx;
            float vy = iy0 + (float)qy;
            float wv = 0.0f; int off = 0;
            if (ux >= 0.0f && ux <= 479.0f && vy >= 0.0f && vy <= 479.0f) {
              int U = (int)ux, V = (int)vy;
              // agent_view nonzero only in rows [240,340), cols [190,290)
              if (U >= 190 && U < 290 && V >= 240 && V < 340) {
                off = (V - 240)*NVR + (U - 190);
                wv = wo * (wix[qx]*wiy[qy]);
              }
            }
            twt[k] = wv; toff[k] = off;
            nz += (wv != 0.0f) ? 1 : 0;
          }
        }
      } else {
        #pragma unroll
        for (int k = 0; k < 4; ++k) { twt[kb+k] = 0.0f; toff[kb+k] = 0; }
      }
    }
  }

  const float* pbase = proj + (size_t)b*NC*NVR*NVR;
  size_t base_idx = (size_t)b*NC*NM*NM + (size_t)h*NM + w;
  if (nz > 0) {
    #pragma unroll 1
    for (int c = 0; c < NC; ++c) {
      size_t idx = base_idx + (size_t)c*NM*NM;
      float ml = maps_last[idx];
      float val = 0.0f;
      if (c != 2 && c != 3) {
        const float* pc = pbase + (size_t)c*NVR*NVR;
        #pragma unroll
        for (int k = 0; k < 16; ++k) val += twt[k]*pc[toff[k]];
      }
      d_out[40000 + idx] = fmaxf(ml, val);
    }
  } else {
    #pragma unroll 1
    for (int c = 0; c < NC; ++c) {
      size_t idx = base_idx + (size_t)c*NM*NM;
      d_out[40000 + idx] = fmaxf(maps_last[idx], 0.0f);
    }
  }
}

extern "C" void kernel_launch(void* const* d_in, const int* in_sizes, int n_in,
                              void* d_out, int out_size, void* d_ws, size_t ws_size,
                              hipStream_t stream)
{
  const float* obs        = (const float*)d_in[0];
  const float* pose_obs   = (const float*)d_in[1];
  const float* maps_last  = (const float*)d_in[2];
  const float* poses_last = (const float*)d_in[3];
  float* out = (float*)d_out;

  // workspace layout
  char* ws = (char*)d_ws;
  float* params = (float*)ws;                                   // 16 floats
  float* vox0   = (float*)(ws + 256);                           // 3,200,000 f
  float* vox1   = (float*)(ws + 256 + 12800000);                // 7,680,000 f
  float* proj   = (float*)(ws + 256 + 12800000 + 30720000);     // 800,000 f

  hipMemsetAsync(vox0, 0, 12800000 + 30720000, stream);

  const float foc = (float)(((double)NW) / 2.0 / tan(79.0 * 0.5 * M_PI / 180.0));

  pose_kernel<<<1, 64, 0, stream>>>(pose_obs, poses_last, out + 40000 + 18432000, params);
  splat_kernel<<<(NB*NH*NW)/256, 256, 0, stream>>>(obs, vox0, vox1, foc);
  project_kernel<<<(NB*NVR*NVR + 255)/256, 256, 0, stream>>>(vox0, vox1, proj, out);
  transform_kernel<<<(NB*NM*NM)/256, 256, 0, stream>>>(maps_last, proj, params, out);
}

// Round 2
// 562.866 us; speedup vs baseline: 5.4181x; 5.4181x over previous
//
#include <hip/hip_runtime.h>
#include <math.h>

#define NB 4
#define NC 20
#define NH 480
#define NW 640
#define NPIX (NH*NW)      // 307200
#define NM 480
#define NVR 100
#define NNZ 80
#define ZLO 13
#define ZHI 25
#define NZB 12
#define NSEM_ 16
#define NBINS 101         // y0 bucket 0..100 (100 = dead)

// exact replication of the reference f32 op chains
__device__ __forceinline__ float p1_chain(float d) {
  float xy1 = d / 5.0f;
  xy1 = (xy1 - 50.0f) / 100.0f * 2.0f;
  return xy1 * 50.0f + 50.0f;
}
__device__ __forceinline__ void p02_chain(float d, int row, int col, float foc,
                                          float& p0, float& p2) {
  float X = ((float)col - 319.5f) * d / foc;
  float Z = ((float)(479 - row) - 239.5f) * d / foc;
  float xy0 = (X + 250.0f) / 5.0f;
  xy0 = (xy0 - 50.0f) / 100.0f * 2.0f;
  float zz = (Z + 88.0f) / 5.0f;
  zz = (zz - 32.0f) / 80.0f * 2.0f;
  p0 = xy0 * 50.0f + 50.0f;
  p2 = zz * 40.0f + 40.0f;
}

// ---------------- pose + affine params ----------------
__global__ __launch_bounds__(64) void pose_kernel(
    const float* __restrict__ pose_obs, const float* __restrict__ poses_last,
    float* __restrict__ out_poses, float* __restrict__ params)
{
  int b = threadIdx.x;
  if (b >= NB) return;
  const float R2D = 57.29577951308232f;
  float plx = poses_last[b*3+0], ply = poses_last[b*3+1], plo = poses_last[b*3+2];
  float dx = pose_obs[b*3+0], dy = pose_obs[b*3+1], dth = pose_obs[b*3+2];
  float r = plo / R2D;
  float sr = sinf(r), cr = cosf(r);
  float yy = ply + dx*sr + dy*cr;
  float xx = plx + dx*cr - dy*sr;
  float oo = plo + dth*R2D;
  oo = fmodf(oo - 180.0f, 360.0f) + 180.0f;
  oo = fmodf(oo + 180.0f, 360.0f) - 180.0f;
  out_poses[b*3+0] = xx;
  out_poses[b*3+1] = yy;
  out_poses[b*3+2] = oo;
  float tx = -((xx*100.0f/5.0f) - 240.0f) / 240.0f;
  float ty = -((yy*100.0f/5.0f) - 240.0f) / 240.0f;
  float th = ((90.0f - oo) * 3.14159274101257324f) / 180.0f;
  params[b*4+0] = cosf(th);
  params[b*4+1] = sinf(th);
  params[b*4+2] = tx;
  params[b*4+3] = ty;
}

// ---------------- histogram by y-bucket ----------------
__global__ __launch_bounds__(256) void hist_kernel(
    const float* __restrict__ obs, int* __restrict__ hist)
{
  int b = blockIdx.x / 300, blk = blockIdx.x % 300;
  __shared__ int lh[NBINS];
  for (int i = threadIdx.x; i < NBINS; i += 256) lh[i] = 0;
  __syncthreads();
  const float4* dp = (const float4*)(obs + ((size_t)b*NC + 3)*NPIX);
  float4 dv = dp[blk*256 + threadIdx.x];
  float dvv[4] = {dv.x, dv.y, dv.z, dv.w};
  #pragma unroll
  for (int k = 0; k < 4; ++k) {
    int y0 = (int)floorf(p1_chain(dvv[k]));
    y0 = min(max(y0, 0), 100);
    atomicAdd(&lh[y0], 1);
  }
  __syncthreads();
  for (int i = threadIdx.x; i < NBINS; i += 256)
    if (lh[i]) atomicAdd(&hist[b*NBINS + i], lh[i]);
}

// ---------------- exclusive scan of 404 bins ----------------
__global__ __launch_bounds__(512) void scan_kernel(
    const int* __restrict__ hist, int* __restrict__ starts, int* __restrict__ cursors)
{
  __shared__ int lh[NB*NBINS];
  __shared__ int ls[NB*NBINS + 1];
  for (int i = threadIdx.x; i < NB*NBINS; i += 512) lh[i] = hist[i];
  __syncthreads();
  if (threadIdx.x == 0) {
    int s = 0;
    for (int i = 0; i < NB*NBINS; ++i) { ls[i] = s; s += lh[i]; }
    ls[NB*NBINS] = s;
  }
  __syncthreads();
  for (int i = threadIdx.x; i < NB*NBINS + 1; i += 512) {
    starts[i] = ls[i];
    if (i < NB*NBINS) cursors[i] = ls[i];
  }
}

// ---------------- scatter pixel records into buckets ----------------
__global__ __launch_bounds__(256) void scatter_kernel(
    const float* __restrict__ obs, int* __restrict__ cursors,
    float4* __restrict__ recs, float foc)
{
  int b = blockIdx.x / 300, blk = blockIdx.x % 300;
  __shared__ int lh[NBINS], lbase[NBINS], loff[NBINS];
  for (int i = threadIdx.x; i < NBINS; i += 256) { lh[i] = 0; loff[i] = 0; }
  __syncthreads();
  int pix0 = (blk*256 + threadIdx.x)*4;
  int row = pix0 / NW;
  int c0 = pix0 - row*NW;   // 4-pixel group never crosses a row (640 % 4 == 0)
  const float4* dp = (const float4*)(obs + ((size_t)b*NC + 3)*NPIX);
  float4 dv = dp[blk*256 + threadIdx.x];
  float dvv[4] = {dv.x, dv.y, dv.z, dv.w};
  float rp0[4], rp1[4], rp2[4]; int rbin[4];
  #pragma unroll
  for (int k = 0; k < 4; ++k) {
    float p1 = p1_chain(dvv[k]);
    float p0, p2;
    p02_chain(dvv[k], row, c0 + k, foc, p0, p2);
    rp0[k] = p0; rp1[k] = p1; rp2[k] = p2;
    int y0 = (int)floorf(p1); y0 = min(max(y0, 0), 100);
    rbin[k] = y0;
    atomicAdd(&lh[y0], 1);
  }
  __syncthreads();
  for (int i = threadIdx.x; i < NBINS; i += 256)
    if (lh[i] > 0) lbase[i] = atomicAdd(&cursors[b*NBINS + i], lh[i]);
  __syncthreads();
  #pragma unroll
  for (int k = 0; k < 4; ++k) {
    int idx = atomicAdd(&loff[rbin[k]], 1);
    recs[lbase[rbin[k]] + idx] =
        make_float4(rp0[k], rp1[k], rp2[k], __int_as_float(pix0 + k));
  }
}

// ---------------- ch0 slab: LDS accumulate + project ----------------
__global__ __launch_bounds__(256) void slab0_kernel(
    const float4* __restrict__ recs, const int* __restrict__ starts,
    float* __restrict__ proj, float* __restrict__ out_fp)
{
  int b = blockIdx.x / NVR, Y = blockIdx.x % NVR;
  __shared__ float g[NVR*81];           // [x][z], z padded 80->81
  for (int i = threadIdx.x; i < NVR*81; i += 256) g[i] = 0.0f;
  __syncthreads();
  if (Y > 0) {
    int lo = starts[b*NBINS + Y - 1];
    int hi = starts[b*NBINS + Y + 1];
    float Yf = (float)Y;
    for (int i = lo + threadIdx.x; i < hi; i += 256) {
      float4 r = recs[i];
      float wy = 1.0f - fabsf(r.y - Yf);
      if (wy <= 0.0f) continue;
      float p0 = r.x, p2 = r.z;
      float fl0 = floorf(p0), fl2 = floorf(p2);
      #pragma unroll
      for (int xo = 0; xo < 2; ++xo) {
        float px = fl0 + (float)xo;
        if (!(px > 0.0f && px < 100.0f)) continue;
        float wxy = (1.0f - fabsf(p0 - px)) * wy;
        if (wxy <= 0.0f) continue;
        int ix = (int)px;
        #pragma unroll
        for (int zo = 0; zo < 2; ++zo) {
          float pz = fl2 + (float)zo;
          if (!(pz > 0.0f && pz < 80.0f)) continue;
          float w = wxy * (1.0f - fabsf(p2 - pz));
          if (w > 0.0f) atomicAdd(&g[ix*81 + (int)pz], w);
        }
      }
    }
  }
  __syncthreads();
  if (threadIdx.x < NVR) {
    int x = threadIdx.x;
    float s_all = 0.0f, s_ag = 0.0f;
    for (int z = 0; z < NNZ; ++z) {
      float v = rintf(g[x*81 + z]);
      s_all += v;
      if (z >= ZLO && z < ZHI) s_ag += v;
    }
    float fp_map = fminf(fmaxf(s_ag, 0.0f), 1.0f);
    float fp_exp = fminf(fmaxf(s_all, 0.0f), 1.0f);
    size_t pb = (((size_t)b*NC + 0)*NVR + Y)*NVR + x;
    proj[pb] = fp_map;
    proj[pb + NVR*NVR] = fp_exp;
    proj[pb + 2*NVR*NVR] = 0.0f;
    proj[pb + 3*NVR*NVR] = 0.0f;
    out_fp[(size_t)b*NVR*NVR + Y*NVR + x] = fp_map;
  }
}

// ---------------- sem slab (8 channels per block) ----------------
__global__ __launch_bounds__(256) void slab1_kernel(
    const float* __restrict__ obs, const float4* __restrict__ recs,
    const int* __restrict__ starts, float* __restrict__ proj)
{
  int half = blockIdx.x & 1;
  int t = blockIdx.x >> 1;
  int b = t / NVR, Y = t % NVR;
  __shared__ float g[NVR*NZB*8];        // [x][z:12][s:8] = 38400 B
  for (int i = threadIdx.x; i < NVR*NZB*8; i += 256) g[i] = 0.0f;
  __syncthreads();
  if (Y > 0) {
    int lo = starts[b*NBINS + Y - 1];
    int hi = starts[b*NBINS + Y + 1];
    float Yf = (float)Y;
    const float* sbase = obs + ((size_t)b*NC + 4 + half*8)*NPIX;
    for (int i = lo + threadIdx.x; i < hi; i += 256) {
      float4 r = recs[i];
      float wy = 1.0f - fabsf(r.y - Yf);
      if (wy <= 0.0f) continue;
      float p2 = r.z;
      float fl2 = floorf(p2);
      float wz[2]; int iz[2]; bool any = false;
      #pragma unroll
      for (int zo = 0; zo < 2; ++zo) {
        float pz = fl2 + (float)zo;
        bool v = (pz >= (float)ZLO) && (pz < (float)ZHI);   // band subsumes (0,80)
        float w = v ? (1.0f - fabsf(p2 - pz)) : 0.0f;
        wz[zo] = w; iz[zo] = v ? ((int)pz - ZLO) : 0;
        any = any || (w > 0.0f);
      }
      if (!any) continue;
      float p0 = r.x;
      float fl0 = floorf(p0);
      int pid = __float_as_int(r.w);
      float sem[8];
      #pragma unroll
      for (int s = 0; s < 8; ++s) sem[s] = sbase[(size_t)s*NPIX + pid];
      #pragma unroll
      for (int xo = 0; xo < 2; ++xo) {
        float px = fl0 + (float)xo;
        if (!(px > 0.0f && px < 100.0f)) continue;
        float wxy = (1.0f - fabsf(p0 - px)) * wy;
        if (wxy <= 0.0f) continue;
        int ix = (int)px;
        #pragma unroll
        for (int zo = 0; zo < 2; ++zo) {
          float w = wxy * wz[zo];
          if (w > 0.0f) {
            float* gb = &g[(ix*NZB + iz[zo])*8];
            #pragma unroll
            for (int s = 0; s < 8; ++s) atomicAdd(&gb[s], w * sem[s]);
          }
        }
      }
    }
  }
  __syncthreads();
  for (int p = threadIdx.x; p < NVR*8; p += 256) {
    int x = p >> 3, s = p & 7;
    float acc = 0.0f;
    #pragma unroll
    for (int z = 0; z < NZB; ++z) acc += rintf(g[(x*NZB + z)*8 + s]);
    float val = fminf(fmaxf(acc / 5.0f, 0.0f), 1.0f);
    proj[(((size_t)b*NC + 4 + half*8 + s)*NVR + Y)*NVR + x] = val;
  }
}

// ---------------- fused rotate+translate grid_sample + max ----------------
__global__ __launch_bounds__(256) void transform_kernel(
    const float* __restrict__ maps_last, const float* __restrict__ proj,
    const float* __restrict__ params, float* __restrict__ d_out)
{
  int tid = blockIdx.x * 256 + threadIdx.x;
  int b = tid / (NM*NM);
  int rem = tid - b*(NM*NM);
  int h = rem / NM;
  int w = rem - h*NM;

  float ct = params[b*4+0];
  float st = params[b*4+1];
  float tx = params[b*4+2];
  float ty = params[b*4+3];

  const float step = 2.0f/479.0f;
  float gx = -1.0f + (float)w * step;
  float gy = -1.0f + (float)h * step;
  float X2 = ((gx + tx) + 1.0f) * 0.5f * 479.0f;
  float Y2 = ((gy + ty) + 1.0f) * 0.5f * 479.0f;
  float x0 = floorf(X2), y0 = floorf(Y2);
  float wox[2] = {(x0 + 1.0f) - X2, X2 - x0};
  float woy[2] = {(y0 + 1.0f) - Y2, Y2 - y0};

  float twt[16];
  int   toff[16];
  int nz = 0;
  #pragma unroll
  for (int oy = 0; oy < 2; ++oy) {
    #pragma unroll
    for (int ox = 0; ox < 2; ++ox) {
      int kb = (oy*2 + ox)*4;
      float cx = x0 + (float)ox;
      float cy = y0 + (float)oy;
      float wo = wox[ox]*woy[oy];
      bool ov = (cx >= 0.0f) && (cx <= 479.0f) && (cy >= 0.0f) && (cy <= 479.0f);
      if (ov) {
        float gxr = -1.0f + cx * step;
        float gyr = -1.0f + cy * step;
        float xr = gxr*ct - gyr*st;
        float yr = gxr*st + gyr*ct;
        float XS = (xr + 1.0f)*0.5f*479.0f;
        float YS = (yr + 1.0f)*0.5f*479.0f;
        float ix0 = floorf(XS), iy0 = floorf(YS);
        float wix[2] = {(ix0+1.0f)-XS, XS-ix0};
        float wiy[2] = {(iy0+1.0f)-YS, YS-iy0};
        #pragma unroll
        for (int qy = 0; qy < 2; ++qy) {
          #pragma unroll
          for (int qx = 0; qx < 2; ++qx) {
            int k = kb + qy*2 + qx;
            float ux = ix0 + (float)qx;
            float vy = iy0 + (float)qy;
            float wv = 0.0f; int off = 0;
            if (ux >= 0.0f && ux <= 479.0f && vy >= 0.0f && vy <= 479.0f) {
              int U = (int)ux, V = (int)vy;
              if (U >= 190 && U < 290 && V >= 240 && V < 340) {
                off = (V - 240)*NVR + (U - 190);
                wv = wo * (wix[qx]*wiy[qy]);
              }
            }
            twt[k] = wv; toff[k] = off;
            nz += (wv != 0.0f) ? 1 : 0;
          }
        }
      } else {
        #pragma unroll
        for (int k = 0; k < 4; ++k) { twt[kb+k] = 0.0f; toff[kb+k] = 0; }
      }
    }
  }

  const float* pbase = proj + (size_t)b*NC*NVR*NVR;
  size_t base_idx = (size_t)b*NC*NM*NM + (size_t)h*NM + w;
  if (nz > 0) {
    #pragma unroll 1
    for (int c = 0; c < NC; ++c) {
      size_t idx = base_idx + (size_t)c*NM*NM;
      float ml = maps_last[idx];
      float val = 0.0f;
      if (c != 2 && c != 3) {
        const float* pc = pbase + (size_t)c*NVR*NVR;
        #pragma unroll
        for (int k = 0; k < 16; ++k) val += twt[k]*pc[toff[k]];
      }
      d_out[40000 + idx] = fmaxf(ml, val);
    }
  } else {
    #pragma unroll 1
    for (int c = 0; c < NC; ++c) {
      size_t idx = base_idx + (size_t)c*NM*NM;
      d_out[40000 + idx] = fmaxf(maps_last[idx], 0.0f);
    }
  }
}

extern "C" void kernel_launch(void* const* d_in, const int* in_sizes, int n_in,
                              void* d_out, int out_size, void* d_ws, size_t ws_size,
                              hipStream_t stream)
{
  const float* obs        = (const float*)d_in[0];
  const float* pose_obs   = (const float*)d_in[1];
  const float* maps_last  = (const float*)d_in[2];
  const float* poses_last = (const float*)d_in[3];
  float* out = (float*)d_out;

  // workspace layout (~22.9 MB total)
  char* ws = (char*)d_ws;
  int*    hist    = (int*)ws;                    // 404 ints
  int*    starts  = (int*)(ws + 2048);           // 405 ints
  int*    cursors = (int*)(ws + 4096);           // 404 ints
  float*  params  = (float*)(ws + 6144);         // 16 floats
  float4* recs    = (float4*)(ws + 8192);        // 1,228,800 * 16 B
  float*  proj    = (float*)(ws + 8192 + 19660800); // 800,000 floats

  hipMemsetAsync(ws, 0, 6144, stream);           // hist/starts/cursors

  const float foc = (float)(((double)NW) / 2.0 / tan(79.0 * 0.5 * M_PI / 180.0));

  pose_kernel<<<1, 64, 0, stream>>>(pose_obs, poses_last, out + 40000 + 18432000, params);
  hist_kernel<<<NB*300, 256, 0, stream>>>(obs, hist);
  scan_kernel<<<1, 512, 0, stream>>>(hist, starts, cursors);
  scatter_kernel<<<NB*300, 256, 0, stream>>>(obs, cursors, recs, foc);
  slab0_kernel<<<NB*NVR, 256, 0, stream>>>(recs, starts, proj, out);
  slab1_kernel<<<NB*NVR*2, 256, 0, stream>>>(obs, recs, starts, proj);
  transform_kernel<<<(NB*NM*NM)/256, 256, 0, stream>>>(maps_last, proj, params, out);
}